// Round 2
// baseline (97.403 us; speedup 1.0000x reference)
//
#include <hip/hip_runtime.h>
#include <math.h>

// Problem constants
#define BB     64
#define SS     8192
#define DD     64
#define NBINS  256
#define TPB    1024          // 16 waves
#define GROUPS 8             // bin-groups per batch -> grid = 64*8 = 512 blocks
#define GBINS  (NBINS / GROUPS)   // 32 bins owned per block
#define SEG    128           // payload slots per bin (mean 32, +17 sigma; pow2)
#define CAPT   (GBINS * SEG) // 4096 payload slots (32 KiB LDS payload)

// Round-11: merged-bin accumulate (8 gathers in flight) + dense staging loads.
//  - single-pass stage+scatter into fixed per-bin segments (2 barriers total)
//  - each wave processes its two bins in ONE loop: 8 independent embedX
//    row-gathers in flight; the two bins' remainder iterations overlap
//  - stale-LDS safe: masked lanes redirect the id to row 0 (zero padding row),
//    weight forced to 0 -> never reads unwritten LDS into an address
//  - staging loads fully dense: T4[tid] / T4[1024+tid] (1 KB/wave/instr);
//    token visit order is irrelevant (scatter by bin)
__global__ __launch_bounds__(TPB, 8) void embedder_fused_kernel(
    const float* __restrict__ T,
    const int*   __restrict__ X_ids,
    const float* __restrict__ embedX,
    const float* __restrict__ embedW,
    float4*      __restrict__ out4)      // [BB][NBINS][16]
{
    __shared__ int      l_sid[CAPT];     // token ids   (16 KiB)
    __shared__ float    l_sw[CAPT];      // token weights (16 KiB)
    __shared__ unsigned l_cur[GBINS];    // absolute scatter cursors

    const int blk    = blockIdx.x;
    const int b      = blk >> 3;
    const int bin_lo = (blk & 7) * GBINS;
    const int tid    = threadIdx.x;
    const int lane   = tid & 63;
    const int wv     = tid >> 6;         // 0..15

    // ---- cursor init: absolute base of each bin's fixed segment ----
    if (tid < GBINS) l_cur[tid] = (unsigned)(tid << 7);   // tid * SEG
    __syncthreads();

    // ---- fused stage + scatter: one pass, 8 tokens/thread, dense vec loads ----
    {
        const float4* __restrict__ T4 = (const float4*)(T     + (size_t)b * SS);
        const int4*   __restrict__ X4 = (const int4*)  (X_ids + (size_t)b * SS);
        const float4 ta = T4[tid];           // tokens 4*tid   .. 4*tid+3
        const float4 tb = T4[TPB + tid];     // tokens 4096+4*tid ..
        const int4   xa = X4[tid];
        const int4   xb = X4[TPB + tid];
        const float tt[8] = { ta.x, ta.y, ta.z, ta.w, tb.x, tb.y, tb.z, tb.w };
        const int   ii[8] = { xa.x, xa.y, xa.z, xa.w, xb.x, xb.y, xb.z, xb.w };

        #pragma unroll
        for (int k = 0; k < 8; ++k) {
            const float t  = tt[k];
            const int   id = ii[k];
            const int bin  = (t < 256.0f) ? (int)t : NBINS;   // NBINS = dummy
            const unsigned rel = (unsigned)(bin - bin_lo);
            if (rel < (unsigned)GBINS) {
                const float w = __expf(embedW[id]);
                const unsigned pos = atomicAdd(&l_cur[rel], 1u);
                if (pos < ((rel + 1u) << 7)) {                // overflow guard
                    l_sid[pos] = id;
                    l_sw[pos]  = w;
                }
            }
        }
    }
    __syncthreads();

    // ---- accumulate: wave wv owns bins {2wv, 2wv+1}, processed together ----
    const int q   = lane & 15;           // which float4 of the 64-float row
    const int sub = lane >> 4;           // token sub-group 0..3
    const float4* __restrict__ ex4 = (const float4*)embedX;

    const int bin0  = wv * 2;
    const int bin1  = wv * 2 + 1;
    const int base0 = bin0 << 7;
    const int base1 = bin1 << 7;
    int cnt0 = (int)l_cur[bin0] - base0;  cnt0 = (cnt0 > SEG) ? SEG : cnt0;
    int cnt1 = (int)l_cur[bin1] - base1;  cnt1 = (cnt1 > SEG) ? SEG : cnt1;
    const int cmax = (cnt0 > cnt1) ? cnt0 : cnt1;

    float4 acc0 = make_float4(0.f, 0.f, 0.f, 0.f);
    float4 acc1 = make_float4(0.f, 0.f, 0.f, 0.f);

    for (int tb = 0; tb < cmax; tb += 16) {
        #pragma unroll
        for (int g = 0; g < 4; ++g) {    // 8 independent gathers in flight
            const int  tk  = tb + g * 4 + sub;
            const bool ok0 = (tk < cnt0);
            const bool ok1 = (tk < cnt1);
            const int  s0  = ok0 ? l_sid[base0 + tk] : 0;   // row 0 = zeros
            const int  s1  = ok1 ? l_sid[base1 + tk] : 0;
            const float w0 = ok0 ? l_sw[base0 + tk] : 0.0f;
            const float w1 = ok1 ? l_sw[base1 + tk] : 0.0f;
            const float4 v0 = ex4[(size_t)s0 * 16 + q];
            const float4 v1 = ex4[(size_t)s1 * 16 + q];
            acc0.x += w0 * v0.x;  acc0.y += w0 * v0.y;
            acc0.z += w0 * v0.z;  acc0.w += w0 * v0.w;
            acc1.x += w1 * v1.x;  acc1.y += w1 * v1.y;
            acc1.z += w1 * v1.z;  acc1.w += w1 * v1.w;
        }
    }

    // fold the 4 token-subgroups (lanes xor 16, then xor 32)
    acc0.x += __shfl_xor(acc0.x, 16, 64); acc0.y += __shfl_xor(acc0.y, 16, 64);
    acc0.z += __shfl_xor(acc0.z, 16, 64); acc0.w += __shfl_xor(acc0.w, 16, 64);
    acc0.x += __shfl_xor(acc0.x, 32, 64); acc0.y += __shfl_xor(acc0.y, 32, 64);
    acc0.z += __shfl_xor(acc0.z, 32, 64); acc0.w += __shfl_xor(acc0.w, 32, 64);
    acc1.x += __shfl_xor(acc1.x, 16, 64); acc1.y += __shfl_xor(acc1.y, 16, 64);
    acc1.z += __shfl_xor(acc1.z, 16, 64); acc1.w += __shfl_xor(acc1.w, 16, 64);
    acc1.x += __shfl_xor(acc1.x, 32, 64); acc1.y += __shfl_xor(acc1.y, 32, 64);
    acc1.z += __shfl_xor(acc1.z, 32, 64); acc1.w += __shfl_xor(acc1.w, 32, 64);

    if (sub == 0) {
        const float inv0 = 1.0f / ((float)cnt0 + 1e-6f);
        const float inv1 = 1.0f / ((float)cnt1 + 1e-6f);
        float4 o0 = make_float4(acc0.x * inv0, acc0.y * inv0,
                                acc0.z * inv0, acc0.w * inv0);
        float4 o1 = make_float4(acc1.x * inv1, acc1.y * inv1,
                                acc1.z * inv1, acc1.w * inv1);
        out4[((size_t)b * NBINS + bin_lo + bin0) * 16 + q] = o0;  // 256B/bin
        out4[((size_t)b * NBINS + bin_lo + bin1) * 16 + q] = o1;
    }
}

extern "C" void kernel_launch(void* const* d_in, const int* in_sizes, int n_in,
                              void* d_out, int out_size, void* d_ws, size_t ws_size,
                              hipStream_t stream) {
    const float* T      = (const float*)d_in[0];
    const int*   X_ids  = (const int*)  d_in[1];
    const float* embedX = (const float*)d_in[2];
    const float* embedW = (const float*)d_in[3];
    float4* out4 = (float4*)d_out;

    embedder_fused_kernel<<<BB * GROUPS, TPB, 0, stream>>>(
        T, X_ids, embedX, embedW, out4);
}